// Round 4
// baseline (749.397 us; speedup 1.0000x reference)
//
#include <hip/hip_runtime.h>
#include <hip/hip_fp16.h>
#include <math.h>

#define N_NODES 100000
#define N_EDGES 1600000
#define IN_DIM 256
#define OUT_DIM 64

// ---- bucketed scatter-aggregate (no CSR sort) ----
#define NB 512                   // buckets
#define RPB 196                  // rows per bucket; 512*196 = 100352 >= N_NODES
#define BCAP 3712                // per-bucket capacity (mean 3125, +10.5 sd)
#define CAP 24                   // per-bucket LDS staging slots (mean 8, Poisson tail ~4e-7/cell)
#define CHUNK_E 4096             // edges per bin block
#define NBIN_BLK ((N_EDGES + CHUNK_E - 1) / CHUNK_E)  // 391

// ---- workspace layout (bytes); no aliasing (bp lives until aggregate) ----
#define X_OFF         0UL          // 12,800,000 B: x[N_NODES][64] fp16
#define BP_OFF        12800000UL   // 7,602,176 B: int bp[NB][BCAP]
#define WIMG_OFF      20500000UL   // 65,536 B: weight image
#define BCUR_OFF      20600000UL   // 2,048 B: int bcur[NB]
// total ~20.6 MB

typedef short bf16x8 __attribute__((ext_vector_type(8)));
typedef float f32x4 __attribute__((ext_vector_type(4)));

// ---------------- Weight -> bf16 hi/lo B-fragment image (64 KB) ----------------
__global__ __launch_bounds__(256) void convert_weight(const float* __restrict__ w,
                                                      ushort* __restrict__ img) {
    const int g = blockIdx.x * 256 + threadIdx.x;  // 0..16383
    const int j = g & 7, l = (g >> 3) & 63, ts = g >> 9;  // ts = t*8+s
    const int s = ts & 7, t = ts >> 3;
    const int k = s * 32 + (l >> 4) * 8 + j;
    const int c = t * 16 + (l & 15);
    const float v = w[k * OUT_DIM + c];
    const unsigned b = __float_as_uint(v);
    const float r = v - __uint_as_float(b & 0xFFFF0000u);  // residual after hi-truncation
    img[(ts * 2 + 0) * 512 + l * 8 + j] = (ushort)(b >> 16);
    img[(ts * 2 + 1) * 512 + l * 8 + j] = (ushort)(__float_as_uint(r) >> 16);
}

// ---------------- GEMM via MFMA, fp32 accuracy by bf16 hi/lo 3-term split ----------------
__global__ __launch_bounds__(256) void gemm_mfma(const float* __restrict__ inputs,
                                                 const ushort* __restrict__ wimg,
                                                 __half* __restrict__ x) {
    __shared__ ushort lds[32768];  // 64 KB -> 2 blocks/CU
    const int tid = threadIdx.x;

    #pragma unroll
    for (int i = 0; i < 16; ++i) {
        const int c = tid + i * 256;  // 16B-chunk index 0..4095
        *(int4*)(lds + c * 8) = *(const int4*)(wimg + c * 8);
    }
    __syncthreads();

    const int wv = tid >> 6, l = tid & 63;
    const int rbase = blockIdx.x * 64 + wv * 16;
    const int arow_idx = rbase + (l & 15);
    const int row_c = arow_idx < N_NODES ? arow_idx : N_NODES - 1;  // clamp loads; stores guarded
    const float* arow = inputs + (size_t)row_c * IN_DIM;
    const int koff = (l >> 4) * 8;

    bf16x8 ah[8], al[8];
    #pragma unroll
    for (int s = 0; s < 8; ++s) {
        const float4 p = *(const float4*)(arow + s * 32 + koff);
        const float4 q = *(const float4*)(arow + s * 32 + koff + 4);
        const float v[8] = {p.x, p.y, p.z, p.w, q.x, q.y, q.z, q.w};
        #pragma unroll
        for (int j = 0; j < 8; ++j) {
            const unsigned b = __float_as_uint(v[j]);
            const float r = v[j] - __uint_as_float(b & 0xFFFF0000u);
            ah[s][j] = (short)(b >> 16);
            al[s][j] = (short)(__float_as_uint(r) >> 16);
        }
    }

    f32x4 acc[4];
    #pragma unroll
    for (int t = 0; t < 4; ++t) acc[t] = (f32x4){0.f, 0.f, 0.f, 0.f};

    const bf16x8* b8 = (const bf16x8*)lds;
    #pragma unroll
    for (int t = 0; t < 4; ++t) {
        #pragma unroll
        for (int s = 0; s < 8; ++s) {
            const bf16x8 bh = b8[((t * 8 + s) * 2 + 0) * 64 + l];
            const bf16x8 blo = b8[((t * 8 + s) * 2 + 1) * 64 + l];
            acc[t] = __builtin_amdgcn_mfma_f32_16x16x32_bf16(ah[s], bh, acc[t], 0, 0, 0);
            acc[t] = __builtin_amdgcn_mfma_f32_16x16x32_bf16(al[s], bh, acc[t], 0, 0, 0);
            acc[t] = __builtin_amdgcn_mfma_f32_16x16x32_bf16(ah[s], blo, acc[t], 0, 0, 0);
        }
    }

    const int mbase = rbase + (l >> 4) * 4;
    #pragma unroll
    for (int reg = 0; reg < 4; ++reg) {
        const int row = mbase + reg;
        if (row < N_NODES) {
            #pragma unroll
            for (int t = 0; t < 4; ++t)
                x[(size_t)row * OUT_DIM + t * 16 + (l & 15)] = __float2half(acc[t][reg]);
        }
    }
}

// ---------------- Bin edges into 512 row-buckets (packed 4B) ----------------
// pack = (rloc << 17) | col, rloc = r - bucket*RPB (<196 -> 9 bits), col < 2^17.
// Only global atomics: one reservation per (block,bucket) = ~200K total.
__global__ __launch_bounds__(256) void bin_kernel(const int* __restrict__ rows,
                                                  const int* __restrict__ cols,
                                                  int* __restrict__ bcur,
                                                  int* __restrict__ bp) {
    __shared__ int lbuf[NB * CAP];   // 49,152 B
    __shared__ int lcnt[NB], ltot[NB], lbase[NB];  // 6,144 B
    const int tid = threadIdx.x;
    lcnt[tid] = 0; lcnt[tid + 256] = 0;
    __syncthreads();

    const int base = blockIdx.x * CHUNK_E;
    #pragma unroll
    for (int g = 0; g < 4; ++g) {
        const int e = base + (g * 256 + tid) * 4;
        if (e < N_EDGES) {  // N_EDGES % 4 == 0, whole int4 in range
            const int4 r4 = *(const int4*)(rows + e);
            const int4 c4 = *(const int4*)(cols + e);
            const int rr[4] = {r4.x, r4.y, r4.z, r4.w};
            const int cc[4] = {c4.x, c4.y, c4.z, c4.w};
            #pragma unroll
            for (int u = 0; u < 4; ++u) {
                const int r = rr[u];
                const int b = r / RPB;                       // const div -> magic mul
                const int pack = ((r - b * RPB) << 17) | cc[u];
                const int p = atomicAdd(&lcnt[b], 1);
                if (p < CAP) {
                    lbuf[b * CAP + p] = pack;
                } else {  // statistically-never spill (kept for unconditional correctness)
                    const int gp = atomicAdd(&bcur[b], 1);
                    bp[b * BCAP + gp] = pack;
                }
            }
        }
    }
    __syncthreads();
    #pragma unroll
    for (int q = 0; q < 2; ++q) {
        const int b = tid + q * 256;
        const int tot = min(lcnt[b], CAP);
        ltot[b] = tot;
        lbase[b] = atomicAdd(&bcur[b], tot);
    }
    __syncthreads();
    // flush: 32-lane group per bucket -> coalesced packed stores (CAP=24 < 32)
    #pragma unroll
    for (int k = 0; k < 64; ++k) {
        const int b = (k << 3) + (tid >> 5);
        const int i = tid & 31;
        if (i < ltot[b]) bp[b * BCAP + lbase[b] + i] = lbuf[b * CAP + i];
    }
}

// ---------------- Bucket-local LDS scatter-aggregate + fused sigmoid ----------------
// One block per bucket: acc[196][64] fp32 in LDS (50KB -> 2 blocks/CU). Each wave
// processes one edge: 64 lanes = 64 cols; gather is one coalesced 128B row read;
// LDS atomicAdd hits bank = lane&31 -> 2-way aliasing (free). No CSR needed.
__global__ __launch_bounds__(256) void aggregate_kernel(const int* __restrict__ bp,
                                                        const int* __restrict__ bcur,
                                                        const __half* __restrict__ x,
                                                        float* __restrict__ out) {
    __shared__ float acc[RPB * OUT_DIM];  // 50,176 B
    const int b = blockIdx.x, tid = threadIdx.x;
    const int w = tid >> 6, lane = tid & 63;

    // zero accumulator
    f32x4* a4 = (f32x4*)acc;
    for (int i = tid; i < RPB * OUT_DIM / 4; i += 256) a4[i] = (f32x4){0.f, 0.f, 0.f, 0.f};
    __syncthreads();

    const int n = bcur[b];
    const unsigned* bb = (const unsigned*)(bp + b * BCAP);

    // edge loop: wave-uniform indices (scalar loads for packs), unroll 8 for MLP
    for (int j0 = w * 8; j0 < n; j0 += 32) {
        #pragma unroll
        for (int u = 0; u < 8; ++u) {
            const int j = j0 + u;
            if (j < n) {  // wave-uniform branch (no divergence)
                const unsigned p = bb[j];
                const int col = p & 0x1FFFF;
                const int rl = p >> 17;
                const float v = __half2float(x[(size_t)col * OUT_DIM + lane]);
                atomicAdd(&acc[rl * OUT_DIM + lane], v);  // ds_add_f32, no return
            }
        }
    }
    __syncthreads();

    // sigmoid + coalesced float4 writeout
    for (int i = tid; i < RPB * (OUT_DIM / 4); i += 256) {
        const int rr = i >> 4, q = i & 15;
        const int row = b * RPB + rr;
        if (row < N_NODES) {
            const float* ap = acc + rr * OUT_DIM + q * 4;
            float4 o;
            o.x = 1.f / (1.f + __expf(-ap[0]));
            o.y = 1.f / (1.f + __expf(-ap[1]));
            o.z = 1.f / (1.f + __expf(-ap[2]));
            o.w = 1.f / (1.f + __expf(-ap[3]));
            *(float4*)(out + (size_t)row * OUT_DIM + q * 4) = o;
        }
    }
}

extern "C" void kernel_launch(void* const* d_in, const int* in_sizes, int n_in,
                              void* d_out, int out_size, void* d_ws, size_t ws_size,
                              hipStream_t stream) {
    const float* inputs = (const float*)d_in[0];
    const int* edge_index = (const int*)d_in[1];  // [2, N_EDGES], int32 on device
    const float* weight = (const float*)d_in[2];
    float* out = (float*)d_out;

    char* ws = (char*)d_ws;
    __half* x        = (__half*)(ws + X_OFF);
    int* bp          = (int*)(ws + BP_OFF);
    ushort* wimg     = (ushort*)(ws + WIMG_OFF);
    int* bcur        = (int*)(ws + BCUR_OFF);

    const int* rows = edge_index;
    const int* cols = edge_index + N_EDGES;

    hipMemsetAsync(bcur, 0, NB * sizeof(int), stream);

    // ---- bucket the edges (no CSR sort needed) ----
    bin_kernel<<<NBIN_BLK, 256, 0, stream>>>(rows, cols, bcur, bp);

    // ---- dense projection ----
    convert_weight<<<64, 256, 0, stream>>>(weight, wimg);
    gemm_mfma<<<(N_NODES + 63) / 64, 256, 0, stream>>>(inputs, wimg, x);

    // ---- bucket-local scatter-aggregate + sigmoid ----
    aggregate_kernel<<<NB, 256, 0, stream>>>(bp, bcur, x, out);
}

// Round 6
// 277.935 us; speedup vs baseline: 2.6963x; 2.6963x over previous
//
#include <hip/hip_runtime.h>
#include <hip/hip_fp16.h>
#include <math.h>

#define N_NODES 100000
#define N_EDGES 1600000
#define IN_DIM 256
#define OUT_DIM 64

// ---- bucketed fused sort+aggregate ----
#define NB 512                   // buckets
#define RPB 196                  // rows per bucket; 512*196 = 100352 >= N_NODES
#define BCAP 3712                // per-bucket capacity (mean 3136, +10 sd)
#define CAP 24                   // per-bucket LDS staging slots in bin (mean 8)
#define CHUNK_E 4096             // edges per bin block
#define NBIN_BLK ((N_EDGES + CHUNK_E - 1) / CHUNK_E)  // 391

// ---- workspace layout (bytes); bp lives until aggregate -> no aliasing ----
#define X_OFF         0UL          // 12,800,000 B: x[N_NODES][64] fp16
#define BP_OFF        12800000UL   // 7,602,176 B: int bp[NB][BCAP]
#define WIMG_OFF      20500000UL   // 65,536 B: weight image
#define BCUR_OFF      20600000UL   // 2,048 B: int bcur[NB]
// total ~20.6 MB

typedef short bf16x8 __attribute__((ext_vector_type(8)));
typedef float f32x4 __attribute__((ext_vector_type(4)));

// ---------------- Weight -> bf16 hi/lo B-fragment image (64 KB) + bcur zero ----------------
__global__ __launch_bounds__(256) void convert_weight(const float* __restrict__ w,
                                                      ushort* __restrict__ img,
                                                      int* __restrict__ bcur) {
    const int g = blockIdx.x * 256 + threadIdx.x;  // 0..16383
    if (g < NB) bcur[g] = 0;                       // replaces hipMemsetAsync (runs before bin)
    const int j = g & 7, l = (g >> 3) & 63, ts = g >> 9;  // ts = t*8+s
    const int s = ts & 7, t = ts >> 3;
    const int k = s * 32 + (l >> 4) * 8 + j;
    const int c = t * 16 + (l & 15);
    const float v = w[k * OUT_DIM + c];
    const unsigned b = __float_as_uint(v);
    const float r = v - __uint_as_float(b & 0xFFFF0000u);  // residual after hi-truncation
    img[(ts * 2 + 0) * 512 + l * 8 + j] = (ushort)(b >> 16);
    img[(ts * 2 + 1) * 512 + l * 8 + j] = (ushort)(__float_as_uint(r) >> 16);
}

// ---------------- GEMM via MFMA, fp32 accuracy by bf16 hi/lo 3-term split ----------------
__global__ __launch_bounds__(256) void gemm_mfma(const float* __restrict__ inputs,
                                                 const ushort* __restrict__ wimg,
                                                 __half* __restrict__ x) {
    __shared__ ushort lds[32768];  // 64 KB -> 2 blocks/CU
    const int tid = threadIdx.x;

    #pragma unroll
    for (int i = 0; i < 16; ++i) {
        const int c = tid + i * 256;  // 16B-chunk index 0..4095
        *(int4*)(lds + c * 8) = *(const int4*)(wimg + c * 8);
    }
    __syncthreads();

    const int wv = tid >> 6, l = tid & 63;
    const int rbase = blockIdx.x * 64 + wv * 16;
    const int arow_idx = rbase + (l & 15);
    const int row_c = arow_idx < N_NODES ? arow_idx : N_NODES - 1;  // clamp loads; stores guarded
    const float* arow = inputs + (size_t)row_c * IN_DIM;
    const int koff = (l >> 4) * 8;

    bf16x8 ah[8], al[8];
    #pragma unroll
    for (int s = 0; s < 8; ++s) {
        const float4 p = *(const float4*)(arow + s * 32 + koff);
        const float4 q = *(const float4*)(arow + s * 32 + koff + 4);
        const float v[8] = {p.x, p.y, p.z, p.w, q.x, q.y, q.z, q.w};
        #pragma unroll
        for (int j = 0; j < 8; ++j) {
            const unsigned b = __float_as_uint(v[j]);
            const float r = v[j] - __uint_as_float(b & 0xFFFF0000u);
            ah[s][j] = (short)(b >> 16);
            al[s][j] = (short)(__float_as_uint(r) >> 16);
        }
    }

    f32x4 acc[4];
    #pragma unroll
    for (int t = 0; t < 4; ++t) acc[t] = (f32x4){0.f, 0.f, 0.f, 0.f};

    const bf16x8* b8 = (const bf16x8*)lds;
    #pragma unroll
    for (int t = 0; t < 4; ++t) {
        #pragma unroll
        for (int s = 0; s < 8; ++s) {
            const bf16x8 bh = b8[((t * 8 + s) * 2 + 0) * 64 + l];
            const bf16x8 blo = b8[((t * 8 + s) * 2 + 1) * 64 + l];
            acc[t] = __builtin_amdgcn_mfma_f32_16x16x32_bf16(ah[s], bh, acc[t], 0, 0, 0);
            acc[t] = __builtin_amdgcn_mfma_f32_16x16x32_bf16(al[s], bh, acc[t], 0, 0, 0);
            acc[t] = __builtin_amdgcn_mfma_f32_16x16x32_bf16(ah[s], blo, acc[t], 0, 0, 0);
        }
    }

    const int mbase = rbase + (l >> 4) * 4;
    #pragma unroll
    for (int reg = 0; reg < 4; ++reg) {
        const int row = mbase + reg;
        if (row < N_NODES) {
            #pragma unroll
            for (int t = 0; t < 4; ++t)
                x[(size_t)row * OUT_DIM + t * 16 + (l & 15)] = __float2half(acc[t][reg]);
        }
    }
}

// ---------------- Bin edges into 512 row-buckets (packed 4B) ----------------
// pack = (rloc << 17) | col, rloc = r - bucket*RPB (<196 -> 9 bits), col < 2^17.
// Only global atomics: one reservation per (block,bucket) = ~200K total.
__global__ __launch_bounds__(256) void bin_kernel(const int* __restrict__ rows,
                                                  const int* __restrict__ cols,
                                                  int* __restrict__ bcur,
                                                  int* __restrict__ bp) {
    __shared__ int lbuf[NB * CAP];   // 49,152 B
    __shared__ int lcnt[NB], ltot[NB], lbase[NB];  // 6,144 B
    const int tid = threadIdx.x;
    lcnt[tid] = 0; lcnt[tid + 256] = 0;
    __syncthreads();

    const int base = blockIdx.x * CHUNK_E;
    #pragma unroll
    for (int g = 0; g < 4; ++g) {
        const int e = base + (g * 256 + tid) * 4;
        if (e < N_EDGES) {  // N_EDGES % 4 == 0, whole int4 in range
            const int4 r4 = *(const int4*)(rows + e);
            const int4 c4 = *(const int4*)(cols + e);
            const int rr[4] = {r4.x, r4.y, r4.z, r4.w};
            const int cc[4] = {c4.x, c4.y, c4.z, c4.w};
            #pragma unroll
            for (int u = 0; u < 4; ++u) {
                const int r = rr[u];
                const int b = r / RPB;                       // const div -> magic mul
                const int pack = ((r - b * RPB) << 17) | cc[u];
                const int p = atomicAdd(&lcnt[b], 1);
                if (p < CAP) {
                    lbuf[b * CAP + p] = pack;
                } else {  // statistically-never spill (guarded against BCAP overflow)
                    const int gp = atomicAdd(&bcur[b], 1);
                    if (gp < BCAP) bp[b * BCAP + gp] = pack;
                }
            }
        }
    }
    __syncthreads();
    #pragma unroll
    for (int q = 0; q < 2; ++q) {
        const int b = tid + q * 256;
        const int tot = min(lcnt[b], CAP);
        ltot[b] = tot;
        lbase[b] = atomicAdd(&bcur[b], tot);
    }
    __syncthreads();
    // flush: 32-lane group per bucket -> coalesced packed stores (CAP=24 < 32)
    #pragma unroll
    for (int k = 0; k < 64; ++k) {
        const int b = (k << 3) + (tid >> 5);
        const int i = tid & 31;
        if (i < ltot[b]) {
            const int gp = lbase[b] + i;
            if (gp < BCAP) bp[b * BCAP + gp] = lbuf[b * CAP + i];  // guard vs overflow
        }
    }
}

// ---------------- Fused LDS sort + pull-aggregate + sigmoid ----------------
// One block per bucket. Phase 1-3: row-group the bucket's packs entirely in LDS
// (histogram -> scan -> place). Phase 4: round-3's proven pull structure — wave =
// 4 edge-groups x 16 lanes, each group gathers a full 128B x-row (8B/lane), cols
// read from LDS. Deletes sort_kernel + sorted_cols/offsets global traffic.
__global__ __launch_bounds__(256) void aggregate_kernel(const int* __restrict__ bp,
                                                        const int* __restrict__ bcur,
                                                        const __half* __restrict__ x,
                                                        float* __restrict__ out) {
    __shared__ int ebuf[BCAP];       // 14,848 B staged packs
    __shared__ int sbuf[BCAP];       // 14,848 B row-grouped cols
    __shared__ int hist[RPB];
    __shared__ int roff[RPB + 1];
    __shared__ int cur[RPB];
    __shared__ int sc[256], sc2[256];
    const int b = blockIdx.x, t = threadIdx.x;
    const int n = min(bcur[b], BCAP);   // defensive clamp (overflow statistically never)
    const int* bb = bp + b * BCAP;

    if (t < RPB) hist[t] = 0;
    __syncthreads();

    // Phase 1: stage + LDS histogram
    for (int i = t; i < n; i += 256) {
        const int v = bb[i];
        ebuf[i] = v;
        atomicAdd(&hist[v >> 17], 1);
    }
    __syncthreads();

    // Phase 2: exclusive scan of hist -> row offsets + cursors
    const int h = (t < RPB) ? hist[t] : 0;
    sc[t] = h; __syncthreads();
    int* src = sc; int* dst = sc2;
    for (int off = 1; off < 256; off <<= 1) {
        const int v = src[t] + ((t >= off) ? src[t - off] : 0);
        dst[t] = v; __syncthreads();
        int* tmp = src; src = dst; dst = tmp;
    }
    if (t < RPB) { const int e = src[t] - h; roff[t] = e; cur[t] = e; }
    if (t == 0) roff[RPB] = n;
    __syncthreads();

    // Phase 3: place (LDS cursor atomics, LDS -> LDS)
    for (int i = t; i < n; i += 256) {
        const int v = ebuf[i];
        const int p = atomicAdd(&cur[v >> 17], 1);
        sbuf[p] = v & 0x1FFFF;
    }
    __syncthreads();

    // Phase 4: pull-aggregate. Wave w handles rows w, w+4, ... (49 rows/wave).
    const int w = t >> 6, lane = t & 63;
    const int g = lane >> 4;       // edge slot 0..3
    const int s = lane & 15;       // column slice: cols 4s..4s+3
    const __half* xs = x + s * 4;

    for (int rl = w; rl < RPB; rl += 4) {
        const int row = b * RPB + rl;
        if (row >= N_NODES) break;         // wave-uniform
        const int start = roff[rl];
        const int end = roff[rl + 1];
        float a0 = 0.f, a1 = 0.f, a2 = 0.f, a3 = 0.f;
        int j = start;
        for (; j + 15 < end; j += 16) {    // 16 edges per pass, 16 gathers in flight
            int c[4];
            #pragma unroll
            for (int u = 0; u < 4; ++u) c[u] = sbuf[j + u * 4 + g];
            #pragma unroll
            for (int u = 0; u < 4; ++u) {
                const uint2 d = *(const uint2*)(xs + (size_t)c[u] * OUT_DIM);
                const float2 f0 = __half22float2(*(const __half2*)&d.x);
                const float2 f1 = __half22float2(*(const __half2*)&d.y);
                a0 += f0.x; a1 += f0.y; a2 += f1.x; a3 += f1.y;
            }
        }
        // tail: up to 15 edges in ONE guarded pass
        #pragma unroll
        for (int u = 0; u < 4; ++u) {
            const int ej = j + u * 4 + g;
            if (ej < end) {
                const int cc = sbuf[ej];
                const uint2 d = *(const uint2*)(xs + (size_t)cc * OUT_DIM);
                const float2 f0 = __half22float2(*(const __half2*)&d.x);
                const float2 f1 = __half22float2(*(const __half2*)&d.y);
                a0 += f0.x; a1 += f0.y; a2 += f1.x; a3 += f1.y;
            }
        }
        // combine the 4 edge-groups (lane bits 4,5)
        a0 += __shfl_xor(a0, 16); a0 += __shfl_xor(a0, 32);
        a1 += __shfl_xor(a1, 16); a1 += __shfl_xor(a1, 32);
        a2 += __shfl_xor(a2, 16); a2 += __shfl_xor(a2, 32);
        a3 += __shfl_xor(a3, 16); a3 += __shfl_xor(a3, 32);

        if (lane < 16) {
            float4 o;
            o.x = 1.f / (1.f + __expf(-a0));
            o.y = 1.f / (1.f + __expf(-a1));
            o.z = 1.f / (1.f + __expf(-a2));
            o.w = 1.f / (1.f + __expf(-a3));
            *(float4*)(out + (size_t)row * OUT_DIM + s * 4) = o;
        }
    }
}

extern "C" void kernel_launch(void* const* d_in, const int* in_sizes, int n_in,
                              void* d_out, int out_size, void* d_ws, size_t ws_size,
                              hipStream_t stream) {
    const float* inputs = (const float*)d_in[0];
    const int* edge_index = (const int*)d_in[1];  // [2, N_EDGES], int32 on device
    const float* weight = (const float*)d_in[2];
    float* out = (float*)d_out;

    char* ws = (char*)d_ws;
    __half* x        = (__half*)(ws + X_OFF);
    int* bp          = (int*)(ws + BP_OFF);
    ushort* wimg     = (ushort*)(ws + WIMG_OFF);
    int* bcur        = (int*)(ws + BCUR_OFF);

    const int* rows = edge_index;
    const int* cols = edge_index + N_EDGES;

    // convert also zeroes bcur (ordered before bin on the stream)
    convert_weight<<<64, 256, 0, stream>>>(weight, wimg, bcur);
    bin_kernel<<<NBIN_BLK, 256, 0, stream>>>(rows, cols, bcur, bp);
    gemm_mfma<<<(N_NODES + 63) / 64, 256, 0, stream>>>(inputs, wimg, x);
    aggregate_kernel<<<NB, 256, 0, stream>>>(bp, bcur, x, out);
}

// Round 7
// 234.183 us; speedup vs baseline: 3.2000x; 1.1868x over previous
//
#include <hip/hip_runtime.h>
#include <hip/hip_fp16.h>
#include <math.h>

#define N_NODES 100000
#define N_EDGES 1600000
#define IN_DIM 256
#define OUT_DIM 64

// ---- bucketed fused sort+aggregate ----
#define NB 512                   // buckets
#define RPB 196                  // rows per bucket; 512*196 = 100352 >= N_NODES
#define BCAP 3712                // per-bucket capacity (mean 3136, +10 sd)
#define CAP 24                   // per-bucket LDS staging slots in bin (mean 8)
#define CHUNK_E 4096             // edges per bin block
#define NBIN_BLK ((N_EDGES + CHUNK_E - 1) / CHUNK_E)  // 391

// ---- workspace layout (bytes); bp lives until aggregate -> no aliasing ----
#define X_OFF         0UL          // 12,800,000 B: x[N_NODES][64] fp16
#define BP_OFF        12800000UL   // 7,602,176 B: int bp[NB][BCAP]
#define WIMG_OFF      20500000UL   // 65,536 B: weight image
#define BCUR_OFF      20600000UL   // 2,048 B: int bcur[NB]
// total ~20.6 MB

typedef short bf16x8 __attribute__((ext_vector_type(8)));
typedef float f32x4 __attribute__((ext_vector_type(4)));

// ---------------- Weight -> bf16 hi/lo B-fragment image (64 KB) + bcur zero ----------------
__global__ __launch_bounds__(256) void convert_weight(const float* __restrict__ w,
                                                      ushort* __restrict__ img,
                                                      int* __restrict__ bcur) {
    const int g = blockIdx.x * 256 + threadIdx.x;  // 0..16383
    if (g < NB) bcur[g] = 0;                       // replaces hipMemsetAsync (runs before bin)
    const int j = g & 7, l = (g >> 3) & 63, ts = g >> 9;  // ts = t*8+s
    const int s = ts & 7, t = ts >> 3;
    const int k = s * 32 + (l >> 4) * 8 + j;
    const int c = t * 16 + (l & 15);
    const float v = w[k * OUT_DIM + c];
    const unsigned b = __float_as_uint(v);
    const float r = v - __uint_as_float(b & 0xFFFF0000u);  // residual after hi-truncation
    img[(ts * 2 + 0) * 512 + l * 8 + j] = (ushort)(b >> 16);
    img[(ts * 2 + 1) * 512 + l * 8 + j] = (ushort)(__float_as_uint(r) >> 16);
}

// ---------------- GEMM via MFMA, fp32 accuracy by bf16 hi/lo 3-term split ----------------
__global__ __launch_bounds__(256) void gemm_mfma(const float* __restrict__ inputs,
                                                 const ushort* __restrict__ wimg,
                                                 __half* __restrict__ x) {
    __shared__ ushort lds[32768];  // 64 KB -> 2 blocks/CU
    const int tid = threadIdx.x;

    #pragma unroll
    for (int i = 0; i < 16; ++i) {
        const int c = tid + i * 256;  // 16B-chunk index 0..4095
        *(int4*)(lds + c * 8) = *(const int4*)(wimg + c * 8);
    }
    __syncthreads();

    const int wv = tid >> 6, l = tid & 63;
    const int rbase = blockIdx.x * 64 + wv * 16;
    const int arow_idx = rbase + (l & 15);
    const int row_c = arow_idx < N_NODES ? arow_idx : N_NODES - 1;  // clamp loads; stores guarded
    const float* arow = inputs + (size_t)row_c * IN_DIM;
    const int koff = (l >> 4) * 8;

    bf16x8 ah[8], al[8];
    #pragma unroll
    for (int s = 0; s < 8; ++s) {
        const float4 p = *(const float4*)(arow + s * 32 + koff);
        const float4 q = *(const float4*)(arow + s * 32 + koff + 4);
        const float v[8] = {p.x, p.y, p.z, p.w, q.x, q.y, q.z, q.w};
        #pragma unroll
        for (int j = 0; j < 8; ++j) {
            const unsigned b = __float_as_uint(v[j]);
            const float r = v[j] - __uint_as_float(b & 0xFFFF0000u);
            ah[s][j] = (short)(b >> 16);
            al[s][j] = (short)(__float_as_uint(r) >> 16);
        }
    }

    f32x4 acc[4];
    #pragma unroll
    for (int t = 0; t < 4; ++t) acc[t] = (f32x4){0.f, 0.f, 0.f, 0.f};

    const bf16x8* b8 = (const bf16x8*)lds;
    #pragma unroll
    for (int t = 0; t < 4; ++t) {
        #pragma unroll
        for (int s = 0; s < 8; ++s) {
            const bf16x8 bh = b8[((t * 8 + s) * 2 + 0) * 64 + l];
            const bf16x8 blo = b8[((t * 8 + s) * 2 + 1) * 64 + l];
            acc[t] = __builtin_amdgcn_mfma_f32_16x16x32_bf16(ah[s], bh, acc[t], 0, 0, 0);
            acc[t] = __builtin_amdgcn_mfma_f32_16x16x32_bf16(al[s], bh, acc[t], 0, 0, 0);
            acc[t] = __builtin_amdgcn_mfma_f32_16x16x32_bf16(ah[s], blo, acc[t], 0, 0, 0);
        }
    }

    const int mbase = rbase + (l >> 4) * 4;
    #pragma unroll
    for (int reg = 0; reg < 4; ++reg) {
        const int row = mbase + reg;
        if (row < N_NODES) {
            #pragma unroll
            for (int t = 0; t < 4; ++t)
                x[(size_t)row * OUT_DIM + t * 16 + (l & 15)] = __float2half(acc[t][reg]);
        }
    }
}

// ---------------- Bin edges into 512 row-buckets (packed 4B) ----------------
// pack = (rloc << 17) | col, rloc = r - bucket*RPB (<196 -> 9 bits), col < 2^17.
// Only global atomics: one reservation per (block,bucket) = ~200K total.
__global__ __launch_bounds__(256) void bin_kernel(const int* __restrict__ rows,
                                                  const int* __restrict__ cols,
                                                  int* __restrict__ bcur,
                                                  int* __restrict__ bp) {
    __shared__ int lbuf[NB * CAP];   // 49,152 B
    __shared__ int lcnt[NB], ltot[NB], lbase[NB];  // 6,144 B
    const int tid = threadIdx.x;
    lcnt[tid] = 0; lcnt[tid + 256] = 0;
    __syncthreads();

    const int base = blockIdx.x * CHUNK_E;
    #pragma unroll
    for (int g = 0; g < 4; ++g) {
        const int e = base + (g * 256 + tid) * 4;
        if (e < N_EDGES) {  // N_EDGES % 4 == 0, whole int4 in range
            const int4 r4 = *(const int4*)(rows + e);
            const int4 c4 = *(const int4*)(cols + e);
            const int rr[4] = {r4.x, r4.y, r4.z, r4.w};
            const int cc[4] = {c4.x, c4.y, c4.z, c4.w};
            #pragma unroll
            for (int u = 0; u < 4; ++u) {
                const int r = rr[u];
                const int b = r / RPB;                       // const div -> magic mul
                const int pack = ((r - b * RPB) << 17) | cc[u];
                const int p = atomicAdd(&lcnt[b], 1);
                if (p < CAP) {
                    lbuf[b * CAP + p] = pack;
                } else {  // statistically-never spill (guarded against BCAP overflow)
                    const int gp = atomicAdd(&bcur[b], 1);
                    if (gp < BCAP) bp[b * BCAP + gp] = pack;
                }
            }
        }
    }
    __syncthreads();
    #pragma unroll
    for (int q = 0; q < 2; ++q) {
        const int b = tid + q * 256;
        const int tot = min(lcnt[b], CAP);
        ltot[b] = tot;
        lbase[b] = atomicAdd(&bcur[b], tot);
    }
    __syncthreads();
    // flush: 32-lane group per bucket -> coalesced packed stores (CAP=24 < 32)
    #pragma unroll
    for (int k = 0; k < 64; ++k) {
        const int b = (k << 3) + (tid >> 5);
        const int i = tid & 31;
        if (i < ltot[b]) {
            const int gp = lbase[b] + i;
            if (gp < BCAP) bp[b * BCAP + gp] = lbuf[b * CAP + i];  // guard vs overflow
        }
    }
}

// ---------------- Fused LDS sort + pull-aggregate + sigmoid (1024 threads) ----------------
// One block per bucket, 16 waves. 2 blocks/CU (wave-limited) -> 32 waves/CU = full
// occupancy, all 512 blocks co-resident in one shot. Phases 1-3 row-group the packs
// in LDS; phase 4 = proven pull gather (4 edge-groups x 16 lanes, 128B x-row/group).
__global__ __launch_bounds__(1024) void aggregate_kernel(const int* __restrict__ bp,
                                                         const int* __restrict__ bcur,
                                                         const __half* __restrict__ x,
                                                         float* __restrict__ out) {
    __shared__ int ebuf[BCAP];       // 14,848 B staged packs
    __shared__ int sbuf[BCAP];       // 14,848 B row-grouped cols
    __shared__ int hist[RPB];
    __shared__ int roff[RPB + 1];
    __shared__ int cur[RPB];
    __shared__ int sc[256], sc2[256];
    const int b = blockIdx.x, t = threadIdx.x;  // t in [0,1024)
    const int n = min(bcur[b], BCAP);   // defensive clamp (overflow statistically never)
    const int* bb = bp + b * BCAP;

    if (t < RPB) hist[t] = 0;
    __syncthreads();

    // Phase 1: stage + LDS histogram (int4-vectorized global reads)
    const int4* bb4 = (const int4*)bb;
    for (int i = t; i * 4 + 3 < n; i += 1024) {
        const int4 v = bb4[i];
        *(int4*)(ebuf + i * 4) = v;
        atomicAdd(&hist[v.x >> 17], 1);
        atomicAdd(&hist[v.y >> 17], 1);
        atomicAdd(&hist[v.z >> 17], 1);
        atomicAdd(&hist[v.w >> 17], 1);
    }
    {   // scalar tail (< 4 packs)
        const int i = (n & ~3) + t;
        if (i < n) {
            const int v = bb[i];
            ebuf[i] = v;
            atomicAdd(&hist[v >> 17], 1);
        }
    }
    __syncthreads();

    // Phase 2: exclusive scan of hist -> row offsets + cursors (first 256 threads
    // do the work; ALL threads hit every barrier)
    if (t < 256) sc[t] = (t < RPB) ? hist[t] : 0;
    __syncthreads();
    int* src = sc; int* dst = sc2;
    for (int off = 1; off < 256; off <<= 1) {
        if (t < 256) dst[t] = src[t] + ((t >= off) ? src[t - off] : 0);
        __syncthreads();
        int* tmp = src; src = dst; dst = tmp;
    }
    if (t < RPB) { const int e = src[t] - hist[t]; roff[t] = e; cur[t] = e; }
    if (t == 0) roff[RPB] = n;
    __syncthreads();

    // Phase 3: place (LDS cursor atomics, LDS -> LDS)
    for (int i = t; i < n; i += 1024) {
        const int v = ebuf[i];
        const int p = atomicAdd(&cur[v >> 17], 1);
        sbuf[p] = v & 0x1FFFF;
    }
    __syncthreads();

    // Phase 4: pull-aggregate. Wave w handles rows w, w+16, ... (~12 rows/wave).
    const int w = t >> 6, lane = t & 63;
    const int g = lane >> 4;       // edge slot 0..3
    const int s = lane & 15;       // column slice: cols 4s..4s+3
    const __half* xs = x + s * 4;

    for (int rl = w; rl < RPB; rl += 16) {
        const int row = b * RPB + rl;
        if (row >= N_NODES) break;         // wave-uniform
        const int start = roff[rl];
        const int end = roff[rl + 1];
        float a0 = 0.f, a1 = 0.f, a2 = 0.f, a3 = 0.f;
        int j = start;
        for (; j + 15 < end; j += 16) {    // 16 edges per pass, 16 gathers in flight
            int c[4];
            #pragma unroll
            for (int u = 0; u < 4; ++u) c[u] = sbuf[j + u * 4 + g];
            #pragma unroll
            for (int u = 0; u < 4; ++u) {
                const uint2 d = *(const uint2*)(xs + (size_t)c[u] * OUT_DIM);
                const float2 f0 = __half22float2(*(const __half2*)&d.x);
                const float2 f1 = __half22float2(*(const __half2*)&d.y);
                a0 += f0.x; a1 += f0.y; a2 += f1.x; a3 += f1.y;
            }
        }
        // tail: up to 15 edges in ONE guarded pass
        #pragma unroll
        for (int u = 0; u < 4; ++u) {
            const int ej = j + u * 4 + g;
            if (ej < end) {
                const int cc = sbuf[ej];
                const uint2 d = *(const uint2*)(xs + (size_t)cc * OUT_DIM);
                const float2 f0 = __half22float2(*(const __half2*)&d.x);
                const float2 f1 = __half22float2(*(const __half2*)&d.y);
                a0 += f0.x; a1 += f0.y; a2 += f1.x; a3 += f1.y;
            }
        }
        // combine the 4 edge-groups (lane bits 4,5)
        a0 += __shfl_xor(a0, 16); a0 += __shfl_xor(a0, 32);
        a1 += __shfl_xor(a1, 16); a1 += __shfl_xor(a1, 32);
        a2 += __shfl_xor(a2, 16); a2 += __shfl_xor(a2, 32);
        a3 += __shfl_xor(a3, 16); a3 += __shfl_xor(a3, 32);

        if (lane < 16) {
            float4 o;
            o.x = 1.f / (1.f + __expf(-a0));
            o.y = 1.f / (1.f + __expf(-a1));
            o.z = 1.f / (1.f + __expf(-a2));
            o.w = 1.f / (1.f + __expf(-a3));
            *(float4*)(out + (size_t)row * OUT_DIM + s * 4) = o;
        }
    }
}

extern "C" void kernel_launch(void* const* d_in, const int* in_sizes, int n_in,
                              void* d_out, int out_size, void* d_ws, size_t ws_size,
                              hipStream_t stream) {
    const float* inputs = (const float*)d_in[0];
    const int* edge_index = (const int*)d_in[1];  // [2, N_EDGES], int32 on device
    const float* weight = (const float*)d_in[2];
    float* out = (float*)d_out;

    char* ws = (char*)d_ws;
    __half* x        = (__half*)(ws + X_OFF);
    int* bp          = (int*)(ws + BP_OFF);
    ushort* wimg     = (ushort*)(ws + WIMG_OFF);
    int* bcur        = (int*)(ws + BCUR_OFF);

    const int* rows = edge_index;
    const int* cols = edge_index + N_EDGES;

    // convert also zeroes bcur (ordered before bin on the stream)
    convert_weight<<<64, 256, 0, stream>>>(weight, wimg, bcur);
    bin_kernel<<<NBIN_BLK, 256, 0, stream>>>(rows, cols, bcur, bp);
    gemm_mfma<<<(N_NODES + 63) / 64, 256, 0, stream>>>(inputs, wimg, x);
    aggregate_kernel<<<NB, 1024, 0, stream>>>(bp, bcur, x, out);
}

// Round 8
// 231.272 us; speedup vs baseline: 3.2403x; 1.0126x over previous
//
#include <hip/hip_runtime.h>
#include <hip/hip_fp16.h>
#include <math.h>

#define N_NODES 100000
#define N_EDGES 1600000
#define IN_DIM 256
#define OUT_DIM 64

// ---- bucketed fused sort+aggregate ----
#define NB 512                   // buckets
#define RPB 196                  // rows per bucket; 512*196 = 100352 >= N_NODES
#define BCAP 3712                // per-bucket capacity (mean 3136, +10 sd)
#define CAP 24                   // per-bucket LDS staging slots in bin (mean 8)
#define CHUNK_E 4096             // edges per bin block
#define NBIN_BLK ((N_EDGES + CHUNK_E - 1) / CHUNK_E)  // 391
#define NGEMM_BLK ((N_NODES + 63) / 64)               // 1563

// ---- workspace layout (bytes); bp lives until aggregate -> no aliasing ----
#define X_OFF         0UL          // 12,800,000 B: x[N_NODES][64] fp16
#define BP_OFF        12800000UL   // 7,602,176 B: int bp[NB][BCAP]
#define WIMG_OFF      20500000UL   // 65,536 B: weight image
#define BCUR_OFF      20600000UL   // 2,048 B: int bcur[NB]
// total ~20.6 MB

typedef short bf16x8 __attribute__((ext_vector_type(8)));
typedef float f32x4 __attribute__((ext_vector_type(4)));

// ---------------- Weight -> bf16 hi/lo B-fragment image (64 KB) + bcur zero ----------------
__global__ __launch_bounds__(256) void convert_weight(const float* __restrict__ w,
                                                      ushort* __restrict__ img,
                                                      int* __restrict__ bcur) {
    const int g = blockIdx.x * 256 + threadIdx.x;  // 0..16383
    if (g < NB) bcur[g] = 0;                       // replaces hipMemsetAsync (runs before bin)
    const int j = g & 7, l = (g >> 3) & 63, ts = g >> 9;  // ts = t*8+s
    const int s = ts & 7, t = ts >> 3;
    const int k = s * 32 + (l >> 4) * 8 + j;
    const int c = t * 16 + (l & 15);
    const float v = w[k * OUT_DIM + c];
    const unsigned b = __float_as_uint(v);
    const float r = v - __uint_as_float(b & 0xFFFF0000u);  // residual after hi-truncation
    img[(ts * 2 + 0) * 512 + l * 8 + j] = (ushort)(b >> 16);
    img[(ts * 2 + 1) * 512 + l * 8 + j] = (ushort)(__float_as_uint(r) >> 16);
}

// ---------------- GEMM body (role A of fused kernel) ----------------
__device__ __forceinline__ void gemm_body(char* smem, int bid,
                                          const float* __restrict__ inputs,
                                          const ushort* __restrict__ wimg,
                                          __half* __restrict__ x) {
    ushort* lds = (ushort*)smem;  // 64 KB
    const int tid = threadIdx.x;

    #pragma unroll
    for (int i = 0; i < 16; ++i) {
        const int c = tid + i * 256;  // 16B-chunk index 0..4095
        *(int4*)(lds + c * 8) = *(const int4*)(wimg + c * 8);
    }
    __syncthreads();

    const int wv = tid >> 6, l = tid & 63;
    const int rbase = bid * 64 + wv * 16;
    const int arow_idx = rbase + (l & 15);
    const int row_c = arow_idx < N_NODES ? arow_idx : N_NODES - 1;  // clamp loads; stores guarded
    const float* arow = inputs + (size_t)row_c * IN_DIM;
    const int koff = (l >> 4) * 8;

    bf16x8 ah[8], al[8];
    #pragma unroll
    for (int s = 0; s < 8; ++s) {
        const float4 p = *(const float4*)(arow + s * 32 + koff);
        const float4 q = *(const float4*)(arow + s * 32 + koff + 4);
        const float v[8] = {p.x, p.y, p.z, p.w, q.x, q.y, q.z, q.w};
        #pragma unroll
        for (int j = 0; j < 8; ++j) {
            const unsigned b = __float_as_uint(v[j]);
            const float r = v[j] - __uint_as_float(b & 0xFFFF0000u);
            ah[s][j] = (short)(b >> 16);
            al[s][j] = (short)(__float_as_uint(r) >> 16);
        }
    }

    f32x4 acc[4];
    #pragma unroll
    for (int t = 0; t < 4; ++t) acc[t] = (f32x4){0.f, 0.f, 0.f, 0.f};

    const bf16x8* b8 = (const bf16x8*)lds;
    #pragma unroll
    for (int t = 0; t < 4; ++t) {
        #pragma unroll
        for (int s = 0; s < 8; ++s) {
            const bf16x8 bh = b8[((t * 8 + s) * 2 + 0) * 64 + l];
            const bf16x8 blo = b8[((t * 8 + s) * 2 + 1) * 64 + l];
            acc[t] = __builtin_amdgcn_mfma_f32_16x16x32_bf16(ah[s], bh, acc[t], 0, 0, 0);
            acc[t] = __builtin_amdgcn_mfma_f32_16x16x32_bf16(al[s], bh, acc[t], 0, 0, 0);
            acc[t] = __builtin_amdgcn_mfma_f32_16x16x32_bf16(ah[s], blo, acc[t], 0, 0, 0);
        }
    }

    const int mbase = rbase + (l >> 4) * 4;
    #pragma unroll
    for (int reg = 0; reg < 4; ++reg) {
        const int row = mbase + reg;
        if (row < N_NODES) {
            #pragma unroll
            for (int t = 0; t < 4; ++t)
                x[(size_t)row * OUT_DIM + t * 16 + (l & 15)] = __float2half(acc[t][reg]);
        }
    }
}

// ---------------- Bin body (role B of fused kernel) ----------------
// pack = (rloc << 17) | col, rloc = r - bucket*RPB (<196 -> 9 bits), col < 2^17.
// Only global atomics: one reservation per (block,bucket) = ~200K total.
__device__ __forceinline__ void bin_body(char* smem, int bid,
                                         const int* __restrict__ rows,
                                         const int* __restrict__ cols,
                                         int* __restrict__ bcur,
                                         int* __restrict__ bp) {
    int* lbuf  = (int*)smem;                  // 49,152 B
    int* lcnt  = (int*)(smem + NB * CAP * 4); // 2,048 B
    int* ltot  = lcnt + NB;
    int* lbase = ltot + NB;                   // total 55,296 B
    const int tid = threadIdx.x;
    lcnt[tid] = 0; lcnt[tid + 256] = 0;
    __syncthreads();

    const int base = bid * CHUNK_E;
    #pragma unroll
    for (int g = 0; g < 4; ++g) {
        const int e = base + (g * 256 + tid) * 4;
        if (e < N_EDGES) {  // N_EDGES % 4 == 0, whole int4 in range
            const int4 r4 = *(const int4*)(rows + e);
            const int4 c4 = *(const int4*)(cols + e);
            const int rr[4] = {r4.x, r4.y, r4.z, r4.w};
            const int cc[4] = {c4.x, c4.y, c4.z, c4.w};
            #pragma unroll
            for (int u = 0; u < 4; ++u) {
                const int r = rr[u];
                const int b = r / RPB;                       // const div -> magic mul
                const int pack = ((r - b * RPB) << 17) | cc[u];
                const int p = atomicAdd(&lcnt[b], 1);
                if (p < CAP) {
                    lbuf[b * CAP + p] = pack;
                } else {  // statistically-never spill (guarded against BCAP overflow)
                    const int gp = atomicAdd(&bcur[b], 1);
                    if (gp < BCAP) bp[b * BCAP + gp] = pack;
                }
            }
        }
    }
    __syncthreads();
    #pragma unroll
    for (int q = 0; q < 2; ++q) {
        const int b = tid + q * 256;
        const int tot = min(lcnt[b], CAP);
        ltot[b] = tot;
        lbase[b] = atomicAdd(&bcur[b], tot);
    }
    __syncthreads();
    // flush: 32-lane group per bucket -> coalesced packed stores (CAP=24 < 32)
    #pragma unroll
    for (int k = 0; k < 64; ++k) {
        const int b = (k << 3) + (tid >> 5);
        const int i = tid & 31;
        if (i < ltot[b]) {
            const int gp = lbase[b] + i;
            if (gp < BCAP) bp[b * BCAP + gp] = lbuf[b * CAP + i];  // guard vs overflow
        }
    }
}

// ---------------- Fused bin + GEMM (independent roles, one launch) ----------------
// Blocks 0..NBIN_BLK-1 bin edges; the rest do the MFMA projection. bin is
// LDS-atomic/latency-bound, gemm is MFMA/LDS-bound -> complementary pipes overlap.
__global__ __launch_bounds__(256) void fused_gemm_bin(const float* __restrict__ inputs,
                                                      const ushort* __restrict__ wimg,
                                                      __half* __restrict__ x,
                                                      const int* __restrict__ rows,
                                                      const int* __restrict__ cols,
                                                      int* __restrict__ bcur,
                                                      int* __restrict__ bp) {
    __shared__ __align__(16) char smem[65536];  // union: gemm 64KB / bin 55.3KB
    if (blockIdx.x < NBIN_BLK)
        bin_body(smem, blockIdx.x, rows, cols, bcur, bp);
    else
        gemm_body(smem, blockIdx.x - NBIN_BLK, inputs, wimg, x);
}

// ---------------- Fused LDS sort + pull-aggregate + sigmoid (1024 threads) ----------------
// One block per bucket, 16 waves -> 2 blocks/CU = 32 waves/CU, all 512 blocks
// co-resident. Phases 1-3 row-group packs in LDS. Phase 4: wave = 8 edge-slots x
// 8 lanes; each 8-lane group reads a full 128B x-row as uint4 (16B/lane) -> half
// the gather instructions of the 8B/lane version, 32 edges per guarded pass.
__global__ __launch_bounds__(1024) void aggregate_kernel(const int* __restrict__ bp,
                                                         const int* __restrict__ bcur,
                                                         const __half* __restrict__ x,
                                                         float* __restrict__ out) {
    __shared__ int ebuf[BCAP];       // 14,848 B staged packs
    __shared__ int sbuf[BCAP];       // 14,848 B row-grouped cols
    __shared__ int hist[RPB];
    __shared__ int roff[RPB + 1];
    __shared__ int cur[RPB];
    __shared__ int sc[256], sc2[256];
    const int b = blockIdx.x, t = threadIdx.x;  // t in [0,1024)
    const int n = min(bcur[b], BCAP);   // defensive clamp (overflow statistically never)
    const int* bb = bp + b * BCAP;

    if (t < RPB) hist[t] = 0;
    __syncthreads();

    // Phase 1: stage + LDS histogram (int4-vectorized global reads)
    const int4* bb4 = (const int4*)bb;
    for (int i = t; i * 4 + 3 < n; i += 1024) {
        const int4 v = bb4[i];
        *(int4*)(ebuf + i * 4) = v;
        atomicAdd(&hist[v.x >> 17], 1);
        atomicAdd(&hist[v.y >> 17], 1);
        atomicAdd(&hist[v.z >> 17], 1);
        atomicAdd(&hist[v.w >> 17], 1);
    }
    {   // scalar tail (< 4 packs)
        const int i = (n & ~3) + t;
        if (i < n) {
            const int v = bb[i];
            ebuf[i] = v;
            atomicAdd(&hist[v >> 17], 1);
        }
    }
    __syncthreads();

    // Phase 2: exclusive scan of hist -> row offsets + cursors (first 256 threads
    // do the work; ALL threads hit every barrier)
    if (t < 256) sc[t] = (t < RPB) ? hist[t] : 0;
    __syncthreads();
    int* src = sc; int* dst = sc2;
    for (int off = 1; off < 256; off <<= 1) {
        if (t < 256) dst[t] = src[t] + ((t >= off) ? src[t - off] : 0);
        __syncthreads();
        int* tmp = src; src = dst; dst = tmp;
    }
    if (t < RPB) { const int e = src[t] - hist[t]; roff[t] = e; cur[t] = e; }
    if (t == 0) roff[RPB] = n;
    __syncthreads();

    // Phase 3: place (LDS cursor atomics, LDS -> LDS)
    for (int i = t; i < n; i += 1024) {
        const int v = ebuf[i];
        const int p = atomicAdd(&cur[v >> 17], 1);
        sbuf[p] = v & 0x1FFFF;
    }
    __syncthreads();

    // Phase 4: pull-aggregate. Wave w handles rows w, w+16, ... (~12 rows/wave).
    const int w = t >> 6, lane = t & 63;
    const int g = lane >> 3;       // edge slot 0..7
    const int s = lane & 7;        // column slice: cols 8s..8s+7 (16B)
    const __half* xs = x + s * 8;

    for (int rl = w; rl < RPB; rl += 16) {
        const int row = b * RPB + rl;
        if (row >= N_NODES) break;         // wave-uniform
        const int start = roff[rl];
        const int end = roff[rl + 1];
        float a[8];
        #pragma unroll
        for (int q = 0; q < 8; ++q) a[q] = 0.f;

        for (int j = start; j < end; j += 32) {   // 32 edges per guarded pass
            #pragma unroll
            for (int u = 0; u < 4; ++u) {
                const int ej = j + u * 8 + g;
                if (ej < end) {
                    const int cc = sbuf[ej];                       // broadcast across 8 lanes
                    const uint4 d = *(const uint4*)(xs + (size_t)cc * OUT_DIM);
                    const __half2* h2 = (const __half2*)&d;
                    #pragma unroll
                    for (int q = 0; q < 4; ++q) {
                        const float2 f = __half22float2(h2[q]);
                        a[2 * q] += f.x; a[2 * q + 1] += f.y;
                    }
                }
            }
        }
        // combine the 8 edge-slots (lane bits 3,4,5)
        #pragma unroll
        for (int q = 0; q < 8; ++q) {
            a[q] += __shfl_xor(a[q], 8);
            a[q] += __shfl_xor(a[q], 16);
            a[q] += __shfl_xor(a[q], 32);
        }

        if (lane < 8) {
            float4 o0, o1;
            o0.x = 1.f / (1.f + __expf(-a[0]));
            o0.y = 1.f / (1.f + __expf(-a[1]));
            o0.z = 1.f / (1.f + __expf(-a[2]));
            o0.w = 1.f / (1.f + __expf(-a[3]));
            o1.x = 1.f / (1.f + __expf(-a[4]));
            o1.y = 1.f / (1.f + __expf(-a[5]));
            o1.z = 1.f / (1.f + __expf(-a[6]));
            o1.w = 1.f / (1.f + __expf(-a[7]));
            float* op = out + (size_t)row * OUT_DIM + s * 8;
            *(float4*)op = o0;
            *(float4*)(op + 4) = o1;
        }
    }
}

extern "C" void kernel_launch(void* const* d_in, const int* in_sizes, int n_in,
                              void* d_out, int out_size, void* d_ws, size_t ws_size,
                              hipStream_t stream) {
    const float* inputs = (const float*)d_in[0];
    const int* edge_index = (const int*)d_in[1];  // [2, N_EDGES], int32 on device
    const float* weight = (const float*)d_in[2];
    float* out = (float*)d_out;

    char* ws = (char*)d_ws;
    __half* x        = (__half*)(ws + X_OFF);
    int* bp          = (int*)(ws + BP_OFF);
    ushort* wimg     = (ushort*)(ws + WIMG_OFF);
    int* bcur        = (int*)(ws + BCUR_OFF);

    const int* rows = edge_index;
    const int* cols = edge_index + N_EDGES;

    // convert zeroes bcur + builds wimg (ordered before fused kernel on the stream)
    convert_weight<<<64, 256, 0, stream>>>(weight, wimg, bcur);
    fused_gemm_bin<<<NBIN_BLK + NGEMM_BLK, 256, 0, stream>>>(inputs, wimg, x,
                                                             rows, cols, bcur, bp);
    aggregate_kernel<<<NB, 1024, 0, stream>>>(bp, bcur, x, out);
}